// Round 8
// baseline (371.761 us; speedup 1.0000x reference)
//
#include <hip/hip_runtime.h>
#include <hip/hip_bf16.h>
#include <cstdint>
#include <math.h>

// ---------------------------------------------------------------------------
// GMemLinear: out = (x @ W^T) + bias, W = jax.random.normal(key(seed),[N,K],f64)
// R8 = R7 resubmit (container died on infra error before any test ran).
// (a) MFMA shape 32x32x16 (ceiling 2495 TF vs 2075 for 16x16x32);
// (b) lane-ordered LDS subtiles (stage-lane l sources exactly what read-lane l
// consumes) -> linear conflict-free ds_read, no swizzle; (c) quad-buffer
// BK=32 pipeline (2 barriers/tile, counted vmcnt(8), setprio) unchanged;
// (d) cast/gen block interleave by bid&3.
// ---------------------------------------------------------------------------

typedef __bf16  bf16x8  __attribute__((ext_vector_type(8)));
typedef float   f32x16  __attribute__((ext_vector_type(16)));
typedef unsigned short u16x8 __attribute__((ext_vector_type(8)));

__device__ __forceinline__ unsigned short f2bf_rne(float f) {
  uint32_t x = __float_as_uint(f);
  uint32_t r = (x + 0x7FFFu + ((x >> 16) & 1u)) >> 16;
  return (unsigned short)r;
}

// Threefry-2x32, 20 rounds (Random123 / JAX).
__device__ __forceinline__ void threefry2x32(uint32_t k0, uint32_t k1,
                                             uint32_t x0, uint32_t x1,
                                             uint32_t& o0, uint32_t& o1) {
  uint32_t ks0 = k0, ks1 = k1, ks2 = k0 ^ k1 ^ 0x1BD11BDAu;
  uint32_t ks[3] = {ks0, ks1, ks2};
  x0 += ks0; x1 += ks1;
  const uint32_t rot0[4] = {13u, 15u, 26u, 6u};
  const uint32_t rot1[4] = {17u, 29u, 16u, 24u};
#pragma unroll
  for (int i = 0; i < 5; ++i) {
    const uint32_t* r = (i & 1) ? rot1 : rot0;
#pragma unroll
    for (int j = 0; j < 4; ++j) {
      x0 += x1;
      x1 = (x1 << r[j]) | (x1 >> (32u - r[j]));
      x1 ^= x0;
    }
    x0 += ks[(i + 1) % 3];
    x1 += ks[(i + 2) % 3] + (uint32_t)(i + 1);
  }
  o0 = x0; o1 = x1;
}

__device__ __forceinline__ double erfinv_mixed(double u) {
  double au = fabs(u);
  double t  = (1.0 - au) * (1.0 + au);
  float  wf = -logf((float)t);
  if (wf < 15.5f) {
    float w, p;
    if (wf < 5.0f) {
      w = wf - 2.5f;
      p = 2.81022636e-08f;
      p = 3.43273939e-07f + p * w;
      p = -3.5233877e-06f + p * w;
      p = -4.39150654e-06f + p * w;
      p = 0.00021858087f + p * w;
      p = -0.00125372503f + p * w;
      p = -0.00417768164f + p * w;
      p = 0.246640727f + p * w;
      p = 1.50140941f + p * w;
    } else {
      w = sqrtf(wf) - 3.0f;
      p = -0.000200214257f;
      p = 0.000100950558f + p * w;
      p = 0.00134934322f + p * w;
      p = -0.00367342844f + p * w;
      p = 0.00573950773f + p * w;
      p = -0.0076224613f + p * w;
      p = 0.00943887047f + p * w;
      p = 1.00167406f + p * w;
      p = 2.83297682f + p * w;
    }
    return (double)(p * (float)u);
  } else {
    double L = -log(1.0 - au);
    double r = sqrt(L);
    r = sqrt(L - log(r) - 0.5723649429247001);
    r = sqrt(L - log(r) - 0.5723649429247001);
    return (u < 0.0) ? -r : r;
  }
}

// ---------------------------------------------------------------------------
// Fused pre-kernel: (bid&3)==0 blocks cast x f32->bf16; others regenerate W.
// ---------------------------------------------------------------------------
__global__ void gen_and_cast(const float* __restrict__ X,
                             unsigned short* __restrict__ Y,
                             unsigned short* __restrict__ W,
                             const int* __restrict__ seedp,
                             int nx, int nw) {
  const int tid = (int)threadIdx.x;
  const int bid = (int)blockIdx.x;
  if ((bid & 3) == 0) {
    const int n8 = nx >> 3;
    const int stride = 2048 * 256;
    for (int q = (int)((bid >> 2) * 256 + tid); q < n8; q += stride) {
      const float4* p = (const float4*)(X + ((size_t)q << 3));
      float4 a = p[0], b = p[1];
      u16x8 o;
      o[0] = f2bf_rne(a.x); o[1] = f2bf_rne(a.y);
      o[2] = f2bf_rne(a.z); o[3] = f2bf_rne(a.w);
      o[4] = f2bf_rne(b.x); o[5] = f2bf_rne(b.y);
      o[6] = f2bf_rne(b.z); o[7] = f2bf_rne(b.w);
      *(u16x8*)(Y + ((size_t)q << 3)) = o;
    }
  } else {
    const uint32_t k1 = (uint32_t)seedp[0];
    const uint32_t k0 = 0u;
    const double DLO = -0x1.fffffffffffffp-1;   // -(1 - 2^-53)
    const int nq = nw >> 2;
    const int gidx = bid - (bid >> 2) - 1;      // 0..6143 over non-cast blocks
    const int stride = 6144 * 256;
    for (int q = gidx * 256 + tid; q < nq; q += stride) {
      ushort4 outv;
      unsigned short tmp[4];
#pragma unroll
      for (int j = 0; j < 4; ++j) {
        uint32_t e = ((uint32_t)q << 2) + (uint32_t)j;
        uint32_t o0, o1;
        threefry2x32(k0, k1, 0u, e, o0, o1);
        uint64_t bits = ((uint64_t)o0 << 32) | (uint64_t)o1;
        uint64_t fb = (bits >> 12) | 0x3FF0000000000000ull;
        union { uint64_t u; double d; } cv; cv.u = fb;
        double f = cv.d - 1.0;
        double u = f * 2.0 + DLO;
        u = fmax(u, DLO);
        double x = erfinv_mixed(u);
        float wv = (float)(1.4142135623730951 * x);
        tmp[j] = f2bf_rne(wv);
      }
      outv.x = tmp[0]; outv.y = tmp[1]; outv.z = tmp[2]; outv.w = tmp[3];
      *(ushort4*)(W + ((size_t)q << 2)) = outv;
    }
  }
}

// ---------------------------------------------------------------------------
// 256x256 GEMM, BK=32, 32x32x16 MFMA, quad-buffer, lane-ordered subtiles.
// Buffer c (32KB): A = 16 subtiles of 1KB at [0,16K)  (rowblock r, khalf h ->
// subtile 2r+h), B = 16 subtiles at [16K,32K). Subtile holds one wave-frag in
// lane order: lane l <-> (row/col = l&31, k-octet = (l>>5)*8). All ds_reads
// are base + lane*16 -> linear, conflict-free, unswizzled.
// ---------------------------------------------------------------------------

__device__ __forceinline__ void gload_lds16(const void* g, void* l) {
  __builtin_amdgcn_global_load_lds(
      (const __attribute__((address_space(1))) unsigned int*)g,
      (__attribute__((address_space(3))) unsigned int*)l, 16, 0, 0);
}

__device__ __forceinline__ uint32_t lds_u32(void* p) {
  return (uint32_t)(uintptr_t)(__attribute__((address_space(3))) char*)p;
}

template <int OFF>
__device__ __forceinline__ bf16x8 dsr16(uint32_t a) {
  bf16x8 r;
  asm volatile("ds_read_b128 %0, %1 offset:%2" : "=v"(r) : "v"(a), "i"(OFF));
  return r;
}

__global__ __launch_bounds__(512, 2) void gemm256(
    const unsigned short* __restrict__ A,   // [M][K] bf16
    const unsigned short* __restrict__ B,   // [N][K] bf16
    const float* __restrict__ bias,         // [N]
    float* __restrict__ C,                  // [M][N] f32
    int M, int N, int K) {
  __shared__ __align__(1024) char lds[131072];

  const int nwg = (int)gridDim.x;
  int wg = (int)blockIdx.x;
  wg = (wg & 7) * (nwg >> 3) + (wg >> 3);       // bijective: nwg % 8 == 0
  const int ntn = N >> 8;
  const int tm = wg / ntn, tn = wg - tm * ntn;

  const int tid = (int)threadIdx.x;
  const int w = tid >> 6, l = tid & 63;
  const int wr = w >> 2, wc = w & 3;            // wave grid 2(M) x 4(N)
  const int l31 = l & 31;
  const int lhi = l >> 5;                       // 0/1 -> k-octet

  const char* Ag = (const char*)A;
  const char* Bg = (const char*)B;
  const long rowA0 = (long)tm * 256;
  const long rowB0 = (long)tn * 256;
  const long Kb = (long)K;

  const uint32_t lds0 = lds_u32(&lds[0]);
  // per-lane read addr (linear within subtile); wave row/col block folded in
  const uint32_t aAddr0 = lds0 + (uint32_t)(wr * 8192 + l * 16);
  const uint32_t bAddr0 = lds0 + 16384u + (uint32_t)(wc * 4096 + l * 16);

  // stage: wave w stages A subtiles u=2w,2w+1 (rowblock w, khalves 0,1) and
  // B subtiles likewise. Source lane l -> (row l&31, k-octet l>>5).
#define STAGE_A(kt_, cs_)                                                     \
  _Pragma("unroll")                                                           \
  for (int i_ = 0; i_ < 2; ++i_) {                                            \
    const int u_ = w * 2 + i_;                                                \
    gload_lds16(Ag + 2 * ((rowA0 + (u_ >> 1) * 32 + l31) * Kb +               \
                          (long)(kt_) * 32 + (u_ & 1) * 16 + lhi * 8),        \
                &lds[(cs_) * 32768 + u_ * 1024]);                             \
  }
#define STAGE_B(kt_, cs_)                                                     \
  _Pragma("unroll")                                                           \
  for (int i_ = 0; i_ < 2; ++i_) {                                            \
    const int u_ = w * 2 + i_;                                                \
    gload_lds16(Bg + 2 * ((rowB0 + (u_ >> 1) * 32 + l31) * Kb +               \
                          (long)(kt_) * 32 + (u_ & 1) * 16 + lhi * 8),        \
                &lds[(cs_) * 32768 + 16384 + u_ * 1024]);                     \
  }

  // A subtile offset = (mi*2 + h)*1024 (mi = rowblock within wave tile);
  // B subtile offset = (ni*2 + h)*1024.
#define ARD(h_)                                                               \
  aq[0] = dsr16<(h_) * 1024>(aA);                                             \
  aq[1] = dsr16<2048 + (h_) * 1024>(aA);                                      \
  aq[2] = dsr16<4096 + (h_) * 1024>(aA);                                      \
  aq[3] = dsr16<6144 + (h_) * 1024>(aA);
#define BRD(h_)                                                               \
  bq[0] = dsr16<(h_) * 1024>(bA);                                             \
  bq[1] = dsr16<2048 + (h_) * 1024>(bA);

#define MFMA8                                                                 \
  _Pragma("unroll")                                                           \
  for (int mi = 0; mi < 4; ++mi)                                              \
    _Pragma("unroll")                                                         \
    for (int ni = 0; ni < 2; ++ni)                                            \
      acc[mi][ni] = __builtin_amdgcn_mfma_f32_32x32x16_bf16(                  \
          aq[mi], bq[ni], acc[mi][ni], 0, 0, 0);

#define LGKM0_FENCE                                                           \
  asm volatile("s_waitcnt lgkmcnt(0)" ::: "memory");                          \
  __builtin_amdgcn_sched_barrier(0);

// One BK=32 tile: c_ = buffer (0..3), kt_ = K-tile index, vm_ = vmcnt literal
// at tile end, st_ = stage tile kt_+3 into (c_+3)&3.
#define TILE_BODY(c_, kt_, vm_, st_)                                          \
  {                                                                           \
    const uint32_t aA = aAddr0 + (c_) * 32768u;                               \
    const uint32_t bA = bAddr0 + (c_) * 32768u;                               \
    bf16x8 aq[4], bq[2];                                                      \
    BRD(0)                                                                    \
    ARD(0)                                                                    \
    if (st_) { STAGE_A((kt_) + 3, ((c_) + 3) & 3) }                           \
    __builtin_amdgcn_s_barrier();                                             \
    LGKM0_FENCE                                                               \
    __builtin_amdgcn_s_setprio(1);                                            \
    MFMA8                                                                     \
    __builtin_amdgcn_s_setprio(0);                                            \
    BRD(1)                                                                    \
    ARD(1)                                                                    \
    if (st_) { STAGE_B((kt_) + 3, ((c_) + 3) & 3) }                           \
    LGKM0_FENCE                                                               \
    __builtin_amdgcn_s_setprio(1);                                            \
    MFMA8                                                                     \
    __builtin_amdgcn_s_setprio(0);                                            \
    asm volatile("s_waitcnt vmcnt(" #vm_ ")" ::: "memory");                   \
    __builtin_amdgcn_sched_barrier(0);                                        \
    __builtin_amdgcn_s_barrier();                                             \
  }

  f32x16 acc[4][2];
#pragma unroll
  for (int i = 0; i < 4; ++i)
#pragma unroll
    for (int j = 0; j < 2; ++j)
#pragma unroll
      for (int e = 0; e < 16; ++e) acc[i][j][e] = 0.f;

  const int NTt = K >> 5;   // 128 K-tiles of BK=32

  // prologue: stage tiles 0,1,2 into buffers 0,1,2 (12 gloads/wave)
  STAGE_A(0, 0) STAGE_B(0, 0)
  STAGE_A(1, 1) STAGE_B(1, 1)
  STAGE_A(2, 2) STAGE_B(2, 2)
  asm volatile("s_waitcnt vmcnt(8)" ::: "memory");   // tile 0's 4 retired
  __builtin_amdgcn_sched_barrier(0);
  __builtin_amdgcn_s_barrier();

  int kt = 0;
  for (; kt + 7 < NTt; kt += 4) {
    TILE_BODY(0, kt,     8, 1)
    TILE_BODY(1, kt + 1, 8, 1)
    TILE_BODY(2, kt + 2, 8, 1)
    TILE_BODY(3, kt + 3, 8, 1)
  }
  // peel: tiles NTt-4 .. NTt-1 (NTt % 4 == 0)
  TILE_BODY(0, kt,     8, 1)   // stages tile NTt-1
  TILE_BODY(1, kt + 1, 4, 0)
  TILE_BODY(2, kt + 2, 0, 0)
  TILE_BODY(3, kt + 3, 0, 0)

  // epilogue: 32x32 C/D layout col = lane&31, row = (reg&3)+8*(reg>>2)+4*(l>>5)
#pragma unroll
  for (int ni = 0; ni < 2; ++ni) {
    const int col = tn * 256 + wc * 64 + ni * 32 + l31;
    const float bv = bias[col];
#pragma unroll
    for (int mi = 0; mi < 4; ++mi) {
      const int r0 = tm * 256 + wr * 128 + mi * 32 + (lhi << 2);
      f32x16 v = acc[mi][ni];
#pragma unroll
      for (int reg = 0; reg < 16; ++reg) {
        const int row = r0 + (reg & 3) + 8 * (reg >> 2);
        C[(size_t)row * N + col] = v[reg] + bv;
      }
    }
  }
#undef STAGE_A
#undef STAGE_B
#undef ARD
#undef BRD
#undef MFMA8
#undef LGKM0_FENCE
#undef TILE_BODY
}

// ---------------------------------------------------------------------------
extern "C" void kernel_launch(void* const* d_in, const int* in_sizes, int n_in,
                              void* d_out, int out_size, void* d_ws, size_t ws_size,
                              hipStream_t stream) {
  const float* x    = (const float*)d_in[0];
  const float* bias = (const float*)d_in[1];
  const int*   seed = (const int*)d_in[2];
  float* out = (float*)d_out;

  const int K = 4096;                       // IN_FEATURES
  const int N = in_sizes[1];                // OUT_FEATURES (4096)
  const int M = in_sizes[0] / K;            // BATCH*SEQ (8192)

  unsigned short* W  = (unsigned short*)d_ws;
  unsigned short* Xb = W + (size_t)N * K;

  gen_and_cast<<<8192, 256, 0, stream>>>(x, Xb, W, seed, M * K, N * K);

  dim3 grid((M / 256) * (N / 256));
  gemm256<<<grid, 512, 0, stream>>>((const unsigned short*)Xb,
                                    (const unsigned short*)W,
                                    bias, out, M, N, K);
}

// Round 9
// 318.678 us; speedup vs baseline: 1.1666x; 1.1666x over previous
//
#include <hip/hip_runtime.h>
#include <hip/hip_bf16.h>
#include <cstdint>
#include <math.h>

// ---------------------------------------------------------------------------
// GMemLinear: out = (x @ W^T) + bias, W = jax.random.normal(key(seed),[N,K],f64)
// R9: base = R6 (16x16x32, swizzled 64B-row staging, quad-buffer BK=32).
// (a) single barrier per tile + counted lgkmcnt(4)/(0) with all 12 ds_reads
//     hoisted to tile top (A4-7 latency hides under MFMA cluster 1);
// (b) genw all-f32 (integer-exact tail via dmin), __logf.
// R8 lesson: lane-ordered subtiles doubled staging VMEM requests (32x32B vs
// 16x64B per gload) -> regression; R6 staging is request-minimal.
// ---------------------------------------------------------------------------

typedef __bf16  bf16x8 __attribute__((ext_vector_type(8)));
typedef float   f32x4  __attribute__((ext_vector_type(4)));
typedef unsigned short u16x8 __attribute__((ext_vector_type(8)));

__device__ __forceinline__ unsigned short f2bf_rne(float f) {
  uint32_t x = __float_as_uint(f);
  uint32_t r = (x + 0x7FFFu + ((x >> 16) & 1u)) >> 16;
  return (unsigned short)r;
}

// Threefry-2x32, 20 rounds (Random123 / JAX).
__device__ __forceinline__ void threefry2x32(uint32_t k0, uint32_t k1,
                                             uint32_t x0, uint32_t x1,
                                             uint32_t& o0, uint32_t& o1) {
  uint32_t ks0 = k0, ks1 = k1, ks2 = k0 ^ k1 ^ 0x1BD11BDAu;
  uint32_t ks[3] = {ks0, ks1, ks2};
  x0 += ks0; x1 += ks1;
  const uint32_t rot0[4] = {13u, 15u, 26u, 6u};
  const uint32_t rot1[4] = {17u, 29u, 16u, 24u};
#pragma unroll
  for (int i = 0; i < 5; ++i) {
    const uint32_t* r = (i & 1) ? rot1 : rot0;
#pragma unroll
    for (int j = 0; j < 4; ++j) {
      x0 += x1;
      x1 = (x1 << r[j]) | (x1 >> (32u - r[j]));
      x1 ^= x0;
    }
    x0 += ks[(i + 1) % 3];
    x1 += ks[(i + 2) % 3] + (uint32_t)(i + 1);
  }
  o0 = x0; o1 = x1;
}

// All-f32 normal from 52-bit mantissa draw. u = 2f-1; t = (1-|u|)(1+|u|)
// computed from integer dmin = min(m, 2^52-m) so the tail keeps full
// precision (f32 u alone would quantize 1-|u| at 2^-24).
__device__ __forceinline__ float normal_from_bits(uint64_t m52) {
  float f = (float)m52 * 0x1p-52f;
  float u = 2.0f * f - 1.0f;
  uint64_t dmin_i = (m52 >= (1ull << 51)) ? ((1ull << 52) - m52) : m52;
  float dminf = fmaxf((float)dmin_i, 0.25f);
  float oma = dminf * 0x1p-51f;            // 1 - |u| (exact-ish)
  float opa = 2.0f - oma;                  // 1 + |u|
  float t = oma * opa;
  float wf = -__logf(t);
  float x;
  if (wf < 15.5f) {
    float w, p;
    if (wf < 5.0f) {
      w = wf - 2.5f;
      p = 2.81022636e-08f;
      p = 3.43273939e-07f + p * w;
      p = -3.5233877e-06f + p * w;
      p = -4.39150654e-06f + p * w;
      p = 0.00021858087f + p * w;
      p = -0.00125372503f + p * w;
      p = -0.00417768164f + p * w;
      p = 0.246640727f + p * w;
      p = 1.50140941f + p * w;
    } else {
      w = sqrtf(wf) - 3.0f;
      p = -0.000200214257f;
      p = 0.000100950558f + p * w;
      p = 0.00134934322f + p * w;
      p = -0.00367342844f + p * w;
      p = 0.00573950773f + p * w;
      p = -0.0076224613f + p * w;
      p = 0.00943887047f + p * w;
      p = 1.00167406f + p * w;
      p = 2.83297682f + p * w;
    }
    x = p * u;
  } else {
    float L = wf + __logf(opa);            // -log(1-|u|)
    float r = sqrtf(L);
    r = sqrtf(L - __logf(r) - 0.57236494f);
    r = sqrtf(L - __logf(r) - 0.57236494f);
    x = (u < 0.0f) ? -r : r;
  }
  return 1.41421356f * x;
}

// ---------------------------------------------------------------------------
// Fused pre-kernel: (bid&3)==0 blocks cast x f32->bf16; others regenerate W.
// ---------------------------------------------------------------------------
__global__ void gen_and_cast(const float* __restrict__ X,
                             unsigned short* __restrict__ Y,
                             unsigned short* __restrict__ W,
                             const int* __restrict__ seedp,
                             int nx, int nw) {
  const int tid = (int)threadIdx.x;
  const int bid = (int)blockIdx.x;
  if ((bid & 3) == 0) {
    const int n8 = nx >> 3;
    const int stride = 2048 * 256;
    for (int q = (int)((bid >> 2) * 256 + tid); q < n8; q += stride) {
      const float4* p = (const float4*)(X + ((size_t)q << 3));
      float4 a = p[0], b = p[1];
      u16x8 o;
      o[0] = f2bf_rne(a.x); o[1] = f2bf_rne(a.y);
      o[2] = f2bf_rne(a.z); o[3] = f2bf_rne(a.w);
      o[4] = f2bf_rne(b.x); o[5] = f2bf_rne(b.y);
      o[6] = f2bf_rne(b.z); o[7] = f2bf_rne(b.w);
      *(u16x8*)(Y + ((size_t)q << 3)) = o;
    }
  } else {
    const uint32_t k1 = (uint32_t)seedp[0];
    const uint32_t k0 = 0u;
    const int nq = nw >> 2;
    const int gidx = bid - (bid >> 2) - 1;      // 0..6143 over non-cast blocks
    const int stride = 6144 * 256;
    for (int q = gidx * 256 + tid; q < nq; q += stride) {
      ushort4 outv;
      unsigned short tmp[4];
#pragma unroll
      for (int j = 0; j < 4; ++j) {
        uint32_t e = ((uint32_t)q << 2) + (uint32_t)j;
        uint32_t o0, o1;
        threefry2x32(k0, k1, 0u, e, o0, o1);
        uint64_t bits = ((uint64_t)o0 << 32) | (uint64_t)o1;
        tmp[j] = f2bf_rne(normal_from_bits(bits >> 12));
      }
      outv.x = tmp[0]; outv.y = tmp[1]; outv.z = tmp[2]; outv.w = tmp[3];
      *(ushort4*)(W + ((size_t)q << 2)) = outv;
    }
  }
}

// ---------------------------------------------------------------------------
// 256x256 GEMM, BK=32, quad-buffer, spread staging, counted vmcnt+lgkmcnt.
// LDS buf c (32KB): A subtiles 0..15 (1KB = 16 rows x 64B), B subtiles at +16K.
// One barrier per tile (end). All 12 ds_reads issued at tile top; cluster 1
// waits lgkmcnt(4), cluster 2 lgkmcnt(0).
// ---------------------------------------------------------------------------

__device__ __forceinline__ void gload_lds16(const void* g, void* l) {
  __builtin_amdgcn_global_load_lds(
      (const __attribute__((address_space(1))) unsigned int*)g,
      (__attribute__((address_space(3))) unsigned int*)l, 16, 0, 0);
}

__device__ __forceinline__ uint32_t lds_u32(void* p) {
  return (uint32_t)(uintptr_t)(__attribute__((address_space(3))) char*)p;
}

template <int OFF>
__device__ __forceinline__ bf16x8 dsr16(uint32_t a) {
  bf16x8 r;
  asm volatile("ds_read_b128 %0, %1 offset:%2" : "=v"(r) : "v"(a), "i"(OFF));
  return r;
}

__global__ __launch_bounds__(512, 2) void gemm256(
    const unsigned short* __restrict__ A,   // [M][K] bf16
    const unsigned short* __restrict__ B,   // [N][K] bf16
    const float* __restrict__ bias,         // [N]
    float* __restrict__ C,                  // [M][N] f32
    int M, int N, int K) {
  __shared__ __align__(1024) char lds[131072];

  const int nwg = (int)gridDim.x;
  int wg = (int)blockIdx.x;
  wg = (wg & 7) * (nwg >> 3) + (wg >> 3);       // bijective: nwg % 8 == 0
  const int ntn = N >> 8;
  const int tm = wg / ntn, tn = wg - tm * ntn;

  const int tid = (int)threadIdx.x;
  const int w = tid >> 6, l = tid & 63;
  const int wr = w >> 2, wc = w & 3;            // wave grid 2(M) x 4(N)
  const int l15 = l & 15;

  // read-side swizzled lane offset within a 1KiB (16row x 64B) subtile
  int laneRd = (l15 << 6) | ((l >> 4) << 4);
  laneRd ^= ((l15 >> 1) & 3) << 4;
  // stage-side: lane l sources global row l>>2, col-slot pre-inverse-swizzled
  const int stRow = l >> 2;
  const int stCol = (((l & 3) ^ ((l >> 3) & 3)) << 4);

  const char* Ag = (const char*)A;
  const char* Bg = (const char*)B;
  const long rowA0 = (long)tm * 256;
  const long rowB0 = (long)tn * 256;
  const long Kb = (long)K;

  const uint32_t lds0  = lds_u32(&lds[0]);
  const uint32_t aBase = lds0 + (uint32_t)(wr * 8192 + laneRd);
  const uint32_t bBase = lds0 + 16384u + (uint32_t)(wc * 4096 + laneRd);

  // stage 2 subtiles (u = w*2, w*2+1) of tile kt_ into buffer cs_
#define STAGE_A(kt_, cs_)                                                     \
  _Pragma("unroll")                                                           \
  for (int i_ = 0; i_ < 2; ++i_) {                                            \
    const int u_ = w * 2 + i_;                                                \
    gload_lds16(Ag + 2 * ((rowA0 + u_ * 16 + stRow) * Kb + (long)(kt_) * 32) + stCol, \
                &lds[(cs_) * 32768 + u_ * 1024]);                             \
  }
#define STAGE_B(kt_, cs_)                                                     \
  _Pragma("unroll")                                                           \
  for (int i_ = 0; i_ < 2; ++i_) {                                            \
    const int u_ = w * 2 + i_;                                                \
    gload_lds16(Bg + 2 * ((rowB0 + u_ * 16 + stRow) * Kb + (long)(kt_) * 32) + stCol, \
                &lds[(cs_) * 32768 + 16384 + u_ * 1024]);                     \
  }

#define MFMA16(base_)                                                         \
  _Pragma("unroll")                                                           \
  for (int mi = 0; mi < 4; ++mi)                                              \
    _Pragma("unroll")                                                         \
    for (int ni = 0; ni < 4; ++ni)                                            \
      acc[(base_) + mi][ni] = __builtin_amdgcn_mfma_f32_16x16x32_bf16(        \
          aq[(base_) + mi], bq[ni], acc[(base_) + mi][ni], 0, 0, 0);

// One BK=32 tile: c_ = buffer (compile-time 0..3), kt_ = K-tile index,
// vm_ = vmcnt literal at tile end, st_ = stage tile kt_+3 into (c_+3)&3.
// Reads issued oldest-first: bq[0..3], aq[0..3], aq[4..7]; DS completes
// in-order -> lgkmcnt(4) guarantees bq+aq[0..3] landed.
#define TILE_BODY(c_, kt_, vm_, st_)                                          \
  {                                                                           \
    const uint32_t aB = aBase + (c_) * 32768u;                                \
    const uint32_t bB = bBase + (c_) * 32768u;                                \
    bf16x8 aq[8], bq[4];                                                      \
    bq[0] = dsr16<0>(bB);    bq[1] = dsr16<1024>(bB);                         \
    bq[2] = dsr16<2048>(bB); bq[3] = dsr16<3072>(bB);                         \
    aq[0] = dsr16<0>(aB);    aq[1] = dsr16<1024>(aB);                         \
    aq[2] = dsr16<2048>(aB); aq[3] = dsr16<3072>(aB);                         \
    aq[4] = dsr16<4096>(aB); aq[5] = dsr16<5120>(aB);                         \
    aq[6] = dsr16<6144>(aB); aq[7] = dsr16<7168>(aB);                         \
    if (st_) { STAGE_A((kt_) + 3, ((c_) + 3) & 3) }                           \
    asm volatile("s_waitcnt lgkmcnt(4)" ::: "memory");                        \
    __builtin_amdgcn_sched_barrier(0);                                        \
    __builtin_amdgcn_s_setprio(1);                                            \
    MFMA16(0)                                                                 \
    __builtin_amdgcn_s_setprio(0);                                            \
    if (st_) { STAGE_B((kt_) + 3, ((c_) + 3) & 3) }                           \
    asm volatile("s_waitcnt lgkmcnt(0)" ::: "memory");                        \
    __builtin_amdgcn_sched_barrier(0);                                        \
    __builtin_amdgcn_s_setprio(1);                                            \
    MFMA16(4)                                                                 \
    __builtin_amdgcn_s_setprio(0);                                            \
    asm volatile("s_waitcnt vmcnt(" #vm_ ")" ::: "memory");                   \
    __builtin_amdgcn_sched_barrier(0);                                        \
    __builtin_amdgcn_s_barrier();                                             \
  }

  f32x4 acc[8][4];
#pragma unroll
  for (int i = 0; i < 8; ++i)
#pragma unroll
    for (int j = 0; j < 4; ++j) acc[i][j] = (f32x4){0.f, 0.f, 0.f, 0.f};

  const int NTt = K >> 5;   // 128 K-tiles of BK=32

  // prologue: stage tiles 0,1,2 into buffers 0,1,2 (12 gloads/wave)
  STAGE_A(0, 0) STAGE_B(0, 0)
  STAGE_A(1, 1) STAGE_B(1, 1)
  STAGE_A(2, 2) STAGE_B(2, 2)
  asm volatile("s_waitcnt vmcnt(8)" ::: "memory");   // tile 0's 4 retired
  __builtin_amdgcn_sched_barrier(0);
  __builtin_amdgcn_s_barrier();

  int kt = 0;
  for (; kt + 7 < NTt; kt += 4) {
    TILE_BODY(0, kt,     8, 1)
    TILE_BODY(1, kt + 1, 8, 1)
    TILE_BODY(2, kt + 2, 8, 1)
    TILE_BODY(3, kt + 3, 8, 1)
  }
  // peel: tiles NTt-4 .. NTt-1 (NTt % 4 == 0)
  TILE_BODY(0, kt,     8, 1)   // stages tile NTt-1
  TILE_BODY(1, kt + 1, 4, 0)
  TILE_BODY(2, kt + 2, 0, 0)
  TILE_BODY(3, kt + 3, 0, 0)

  // epilogue: C/D layout col = lane&15, row = (lane>>4)*4 + j
#pragma unroll
  for (int ni = 0; ni < 4; ++ni) {
    const int col = tn * 256 + wc * 64 + ni * 16 + l15;
    const float bv = bias[col];
#pragma unroll
    for (int mi = 0; mi < 8; ++mi) {
      const int r0 = tm * 256 + wr * 128 + mi * 16 + ((l >> 4) << 2);
      f32x4 v = acc[mi][ni];
#pragma unroll
      for (int j = 0; j < 4; ++j)
        C[(size_t)(r0 + j) * N + col] = v[j] + bv;
    }
  }
#undef STAGE_A
#undef STAGE_B
#undef MFMA16
#undef TILE_BODY
}

// ---------------------------------------------------------------------------
extern "C" void kernel_launch(void* const* d_in, const int* in_sizes, int n_in,
                              void* d_out, int out_size, void* d_ws, size_t ws_size,
                              hipStream_t stream) {
  const float* x    = (const float*)d_in[0];
  const float* bias = (const float*)d_in[1];
  const int*   seed = (const int*)d_in[2];
  float* out = (float*)d_out;

  const int K = 4096;                       // IN_FEATURES
  const int N = in_sizes[1];                // OUT_FEATURES (4096)
  const int M = in_sizes[0] / K;            // BATCH*SEQ (8192)

  unsigned short* W  = (unsigned short*)d_ws;
  unsigned short* Xb = W + (size_t)N * K;

  gen_and_cast<<<8192, 256, 0, stream>>>(x, Xb, W, seed, M * K, N * K);

  dim3 grid((M / 256) * (N / 256));
  gemm256<<<grid, 512, 0, stream>>>((const unsigned short*)Xb,
                                    (const unsigned short*)W,
                                    bias, out, M, N, K);
}

// Round 11
// 315.650 us; speedup vs baseline: 1.1778x; 1.0096x over previous
//
#include <hip/hip_runtime.h>
#include <hip/hip_bf16.h>
#include <cstdint>
#include <math.h>

// ---------------------------------------------------------------------------
// GMemLinear: out = (x @ W^T) + bias, W = jax.random.normal(key(seed),[N,K],f64)
// R11 = R10 with the prefetch race fixed: per-tile vmcnt 8 -> 4 (each wave
// retires staging <= t+2 BEFORE the end-of-t barrier, so a pre-barrier
// prefetch of buf t+1 is cross-wave safe); prologue prefetch moved AFTER the
// prologue barrier; peel vmcnt (4,0,0,0). genw = R8-measured f64-lite.
// ---------------------------------------------------------------------------

typedef __bf16  bf16x8 __attribute__((ext_vector_type(8)));
typedef float   f32x4  __attribute__((ext_vector_type(4)));
typedef unsigned short u16x8 __attribute__((ext_vector_type(8)));

__device__ __forceinline__ unsigned short f2bf_rne(float f) {
  uint32_t x = __float_as_uint(f);
  uint32_t r = (x + 0x7FFFu + ((x >> 16) & 1u)) >> 16;
  return (unsigned short)r;
}

// Threefry-2x32, 20 rounds (Random123 / JAX).
__device__ __forceinline__ void threefry2x32(uint32_t k0, uint32_t k1,
                                             uint32_t x0, uint32_t x1,
                                             uint32_t& o0, uint32_t& o1) {
  uint32_t ks0 = k0, ks1 = k1, ks2 = k0 ^ k1 ^ 0x1BD11BDAu;
  uint32_t ks[3] = {ks0, ks1, ks2};
  x0 += ks0; x1 += ks1;
  const uint32_t rot0[4] = {13u, 15u, 26u, 6u};
  const uint32_t rot1[4] = {17u, 29u, 16u, 24u};
#pragma unroll
  for (int i = 0; i < 5; ++i) {
    const uint32_t* r = (i & 1) ? rot1 : rot0;
#pragma unroll
    for (int j = 0; j < 4; ++j) {
      x0 += x1;
      x1 = (x1 << r[j]) | (x1 >> (32u - r[j]));
      x1 ^= x0;
    }
    x0 += ks[(i + 1) % 3];
    x1 += ks[(i + 2) % 3] + (uint32_t)(i + 1);
  }
  o0 = x0; o1 = x1;
}

__device__ __forceinline__ double erfinv_mixed(double u) {
  double au = fabs(u);
  double t  = (1.0 - au) * (1.0 + au);
  float  wf = -logf((float)t);
  if (wf < 15.5f) {
    float w, p;
    if (wf < 5.0f) {
      w = wf - 2.5f;
      p = 2.81022636e-08f;
      p = 3.43273939e-07f + p * w;
      p = -3.5233877e-06f + p * w;
      p = -4.39150654e-06f + p * w;
      p = 0.00021858087f + p * w;
      p = -0.00125372503f + p * w;
      p = -0.00417768164f + p * w;
      p = 0.246640727f + p * w;
      p = 1.50140941f + p * w;
    } else {
      w = sqrtf(wf) - 3.0f;
      p = -0.000200214257f;
      p = 0.000100950558f + p * w;
      p = 0.00134934322f + p * w;
      p = -0.00367342844f + p * w;
      p = 0.00573950773f + p * w;
      p = -0.0076224613f + p * w;
      p = 0.00943887047f + p * w;
      p = 1.00167406f + p * w;
      p = 2.83297682f + p * w;
    }
    return (double)(p * (float)u);
  } else {
    double L = -log(1.0 - au);
    double r = sqrt(L);
    r = sqrt(L - log(r) - 0.5723649429247001);
    r = sqrt(L - log(r) - 0.5723649429247001);
    return (u < 0.0) ? -r : r;
  }
}

// ---------------------------------------------------------------------------
// Fused pre-kernel: (bid&3)==0 blocks cast x f32->bf16; others regenerate W.
// ---------------------------------------------------------------------------
__global__ void gen_and_cast(const float* __restrict__ X,
                             unsigned short* __restrict__ Y,
                             unsigned short* __restrict__ W,
                             const int* __restrict__ seedp,
                             int nx, int nw) {
  const int tid = (int)threadIdx.x;
  const int bid = (int)blockIdx.x;
  if ((bid & 3) == 0) {
    const int n8 = nx >> 3;
    const int stride = 2048 * 256;
    for (int q = (int)((bid >> 2) * 256 + tid); q < n8; q += stride) {
      const float4* p = (const float4*)(X + ((size_t)q << 3));
      float4 a = p[0], b = p[1];
      u16x8 o;
      o[0] = f2bf_rne(a.x); o[1] = f2bf_rne(a.y);
      o[2] = f2bf_rne(a.z); o[3] = f2bf_rne(a.w);
      o[4] = f2bf_rne(b.x); o[5] = f2bf_rne(b.y);
      o[6] = f2bf_rne(b.z); o[7] = f2bf_rne(b.w);
      *(u16x8*)(Y + ((size_t)q << 3)) = o;
    }
  } else {
    const uint32_t k1 = (uint32_t)seedp[0];
    const uint32_t k0 = 0u;
    const double DLO = -0x1.fffffffffffffp-1;   // -(1 - 2^-53)
    const int nq = nw >> 2;
    const int gidx = bid - (bid >> 2) - 1;      // 0..6143 over non-cast blocks
    const int stride = 6144 * 256;
    for (int q = gidx * 256 + tid; q < nq; q += stride) {
      ushort4 outv;
      unsigned short tmp[4];
#pragma unroll
      for (int j = 0; j < 4; ++j) {
        uint32_t e = ((uint32_t)q << 2) + (uint32_t)j;
        uint32_t o0, o1;
        threefry2x32(k0, k1, 0u, e, o0, o1);
        uint64_t bits = ((uint64_t)o0 << 32) | (uint64_t)o1;
        uint64_t fb = (bits >> 12) | 0x3FF0000000000000ull;
        union { uint64_t u; double d; } cv; cv.u = fb;
        double f = cv.d - 1.0;
        double u = f * 2.0 + DLO;
        u = fmax(u, DLO);
        double x = erfinv_mixed(u);
        float wv = (float)(1.4142135623730951 * x);
        tmp[j] = f2bf_rne(wv);
      }
      outv.x = tmp[0]; outv.y = tmp[1]; outv.z = tmp[2]; outv.w = tmp[3];
      *(ushort4*)(W + ((size_t)q << 2)) = outv;
    }
  }
}

// ---------------------------------------------------------------------------
// 256x256 GEMM, BK=32, quad-buffer, cross-barrier register prefetch.
// Safety argument (vmcnt(4) version):
//   - end-of-tile-t vmcnt(4): this wave retired staging <= t+2 (only t+3's
//     4 loads remain). Hence AFTER the end-of-t barrier, ALL waves have
//     retired staging <= t+2.
//   - PREFETCH of buf (t+1)%4 at end of tile t (pre-barrier): every other
//     wave retired t+1's staging before the end-of-(t-1) barrier. SAFE.
//   - WAR: STAGE at tile t writes buf (t-1)%4, whose reads completed at
//     tile t-1's lgkmcnt(0), before the end-of-(t-1) barrier. SAFE.
//   - Peel: vmcnt(0) at NTt-3 so the final tile's prefetch is covered.
// ---------------------------------------------------------------------------

__device__ __forceinline__ void gload_lds16(const void* g, void* l) {
  __builtin_amdgcn_global_load_lds(
      (const __attribute__((address_space(1))) unsigned int*)g,
      (__attribute__((address_space(3))) unsigned int*)l, 16, 0, 0);
}

__device__ __forceinline__ uint32_t lds_u32(void* p) {
  return (uint32_t)(uintptr_t)(__attribute__((address_space(3))) char*)p;
}

template <int OFF>
__device__ __forceinline__ bf16x8 dsr16(uint32_t a) {
  bf16x8 r;
  asm volatile("ds_read_b128 %0, %1 offset:%2" : "=v"(r) : "v"(a), "i"(OFF));
  return r;
}

__global__ __launch_bounds__(512, 2) void gemm256(
    const unsigned short* __restrict__ A,   // [M][K] bf16
    const unsigned short* __restrict__ B,   // [N][K] bf16
    const float* __restrict__ bias,         // [N]
    float* __restrict__ C,                  // [M][N] f32
    int M, int N, int K) {
  __shared__ __align__(1024) char lds[131072];

  const int nwg = (int)gridDim.x;
  int wg = (int)blockIdx.x;
  wg = (wg & 7) * (nwg >> 3) + (wg >> 3);       // bijective: nwg % 8 == 0
  const int ntn = N >> 8;
  const int tm = wg / ntn, tn = wg - tm * ntn;

  const int tid = (int)threadIdx.x;
  const int w = tid >> 6, l = tid & 63;
  const int wr = w >> 2, wc = w & 3;            // wave grid 2(M) x 4(N)
  const int l15 = l & 15;

  // read-side swizzled lane offset within a 1KiB (16row x 64B) subtile
  int laneRd = (l15 << 6) | ((l >> 4) << 4);
  laneRd ^= ((l15 >> 1) & 3) << 4;
  // stage-side: lane l sources global row l>>2, col-slot pre-inverse-swizzled
  const int stRow = l >> 2;
  const int stCol = (((l & 3) ^ ((l >> 3) & 3)) << 4);

  const char* Ag = (const char*)A;
  const char* Bg = (const char*)B;
  const long rowA0 = (long)tm * 256;
  const long rowB0 = (long)tn * 256;
  const long Kb = (long)K;

  const uint32_t lds0  = lds_u32(&lds[0]);
  const uint32_t aBase = lds0 + (uint32_t)(wr * 8192 + laneRd);
  const uint32_t bBase = lds0 + 16384u + (uint32_t)(wc * 4096 + laneRd);

  // stage 2 subtiles (u = w*2, w*2+1) of tile kt_ into buffer cs_
#define STAGE_A(kt_, cs_)                                                     \
  _Pragma("unroll")                                                           \
  for (int i_ = 0; i_ < 2; ++i_) {                                            \
    const int u_ = w * 2 + i_;                                                \
    gload_lds16(Ag + 2 * ((rowA0 + u_ * 16 + stRow) * Kb + (long)(kt_) * 32) + stCol, \
                &lds[(cs_) * 32768 + u_ * 1024]);                             \
  }
#define STAGE_B(kt_, cs_)                                                     \
  _Pragma("unroll")                                                           \
  for (int i_ = 0; i_ < 2; ++i_) {                                            \
    const int u_ = w * 2 + i_;                                                \
    gload_lds16(Bg + 2 * ((rowB0 + u_ * 16 + stRow) * Kb + (long)(kt_) * 32) + stCol, \
                &lds[(cs_) * 32768 + 16384 + u_ * 1024]);                     \
  }

  // issue the 12 fragment reads for buffer cn_
#define PREFETCH(cn_)                                                         \
  {                                                                           \
    const uint32_t aB = aBase + (cn_) * 32768u;                               \
    const uint32_t bB = bBase + (cn_) * 32768u;                               \
    bq[0] = dsr16<0>(bB);    bq[1] = dsr16<1024>(bB);                         \
    bq[2] = dsr16<2048>(bB); bq[3] = dsr16<3072>(bB);                         \
    aq[0] = dsr16<0>(aB);    aq[1] = dsr16<1024>(aB);                         \
    aq[2] = dsr16<2048>(aB); aq[3] = dsr16<3072>(aB);                         \
    aq[4] = dsr16<4096>(aB); aq[5] = dsr16<5120>(aB);                         \
    aq[6] = dsr16<6144>(aB); aq[7] = dsr16<7168>(aB);                         \
  }

#define MFMA16(base_)                                                         \
  _Pragma("unroll")                                                           \
  for (int mi = 0; mi < 4; ++mi)                                              \
    _Pragma("unroll")                                                         \
    for (int ni = 0; ni < 4; ++ni)                                            \
      acc[(base_) + mi][ni] = __builtin_amdgcn_mfma_f32_16x16x32_bf16(        \
          aq[(base_) + mi], bq[ni], acc[(base_) + mi][ni], 0, 0, 0);

// One BK=32 tile. Entry invariant: this tile's 12 ds_reads already issued.
#define TILE_BODY(c_, kt_, vm_, st_, pf_)                                     \
  {                                                                           \
    asm volatile("s_waitcnt lgkmcnt(4)" ::: "memory");                        \
    __builtin_amdgcn_sched_barrier(0);                                        \
    __builtin_amdgcn_s_setprio(1);                                            \
    MFMA16(0)                                                                 \
    __builtin_amdgcn_s_setprio(0);                                            \
    if (st_) { STAGE_A((kt_) + 3, ((c_) + 3) & 3) }                           \
    asm volatile("s_waitcnt lgkmcnt(0)" ::: "memory");                        \
    __builtin_amdgcn_sched_barrier(0);                                        \
    __builtin_amdgcn_s_setprio(1);                                            \
    MFMA16(4)                                                                 \
    __builtin_amdgcn_s_setprio(0);                                            \
    if (st_) { STAGE_B((kt_) + 3, ((c_) + 3) & 3) }                           \
    asm volatile("s_waitcnt vmcnt(" #vm_ ")" ::: "memory");                   \
    __builtin_amdgcn_sched_barrier(0);                                        \
    if (pf_) { PREFETCH(((c_) + 1) & 3) }                                     \
    __builtin_amdgcn_s_barrier();                                             \
  }

  f32x4 acc[8][4];
#pragma unroll
  for (int i = 0; i < 8; ++i)
#pragma unroll
    for (int j = 0; j < 4; ++j) acc[i][j] = (f32x4){0.f, 0.f, 0.f, 0.f};

  bf16x8 aq[8], bq[4];

  const int NTt = K >> 5;   // 128 K-tiles of BK=32

  // prologue: stage tiles 0,1,2; vmcnt(4) retires tiles 0 AND 1 (leaves
  // tile 2's 4); barrier (all waves' tile-0/1 staging now visible);
  // THEN issue tile 0's fragment reads (post-barrier -> race-free).
  STAGE_A(0, 0) STAGE_B(0, 0)
  STAGE_A(1, 1) STAGE_B(1, 1)
  STAGE_A(2, 2) STAGE_B(2, 2)
  asm volatile("s_waitcnt vmcnt(4)" ::: "memory");
  __builtin_amdgcn_sched_barrier(0);
  __builtin_amdgcn_s_barrier();
  PREFETCH(0)

  int kt = 0;
  for (; kt + 7 < NTt; kt += 4) {
    TILE_BODY(0, kt,     4, 1, 1)
    TILE_BODY(1, kt + 1, 4, 1, 1)
    TILE_BODY(2, kt + 2, 4, 1, 1)
    TILE_BODY(3, kt + 3, 4, 1, 1)
  }
  // peel: tiles NTt-4 .. NTt-1 (NTt % 4 == 0). vmcnt(0) at NTt-3 covers the
  // final tile's prefetch cross-wave; later waits trivially satisfied.
  TILE_BODY(0, kt,     4, 1, 1)   // stages tile NTt-1
  TILE_BODY(1, kt + 1, 0, 0, 1)
  TILE_BODY(2, kt + 2, 0, 0, 1)
  TILE_BODY(3, kt + 3, 0, 0, 0)

  // epilogue: C/D layout col = lane&15, row = (lane>>4)*4 + j
#pragma unroll
  for (int ni = 0; ni < 4; ++ni) {
    const int col = tn * 256 + wc * 64 + ni * 16 + l15;
    const float bv = bias[col];
#pragma unroll
    for (int mi = 0; mi < 8; ++mi) {
      const int r0 = tm * 256 + wr * 128 + mi * 16 + ((l >> 4) << 2);
      f32x4 v = acc[mi][ni];
#pragma unroll
      for (int j = 0; j < 4; ++j)
        C[(size_t)(r0 + j) * N + col] = v[j] + bv;
    }
  }
#undef STAGE_A
#undef STAGE_B
#undef PREFETCH
#undef MFMA16
#undef TILE_BODY
}

// ---------------------------------------------------------------------------
extern "C" void kernel_launch(void* const* d_in, const int* in_sizes, int n_in,
                              void* d_out, int out_size, void* d_ws, size_t ws_size,
                              hipStream_t stream) {
  const float* x    = (const float*)d_in[0];
  const float* bias = (const float*)d_in[1];
  const int*   seed = (const int*)d_in[2];
  float* out = (float*)d_out;

  const int K = 4096;                       // IN_FEATURES
  const int N = in_sizes[1];                // OUT_FEATURES (4096)
  const int M = in_sizes[0] / K;            // BATCH*SEQ (8192)

  unsigned short* W  = (unsigned short*)d_ws;
  unsigned short* Xb = W + (size_t)N * K;

  gen_and_cast<<<8192, 256, 0, stream>>>(x, Xb, W, seed, M * K, N * K);

  dim3 grid((M / 256) * (N / 256));
  gemm256<<<grid, 512, 0, stream>>>((const unsigned short*)Xb,
                                    (const unsigned short*)W,
                                    bias, out, M, N, K);
}